// Round 5
// baseline (291.113 us; speedup 1.0000x reference)
//
#include <hip/hip_runtime.h>
#include <math.h>

#define NB 8
#define CH 512
#define NTOK 1024

typedef short          bf16x8 __attribute__((ext_vector_type(8)));
typedef unsigned short u16x8  __attribute__((ext_vector_type(8)));
typedef unsigned short u16x4  __attribute__((ext_vector_type(4)));
typedef unsigned short u16x2  __attribute__((ext_vector_type(2)));
typedef float          f32x4  __attribute__((ext_vector_type(4)));

__device__ __forceinline__ float bf2f(unsigned short u) {
    unsigned int x = ((unsigned int)u) << 16;
    return __builtin_bit_cast(float, x);
}
__device__ __forceinline__ unsigned short f2bf(float f) {
    unsigned int x = __builtin_bit_cast(unsigned int, f);
    x += 0x7fff + ((x >> 16) & 1);   // RNE
    return (unsigned short)(x >> 16);
}

// ---------------- GroupNorm stats: one block per (b, group) ----------------
__global__ __launch_bounds__(256) void stats_kernel(
    const float* __restrict__ x, float* __restrict__ stats)
{
    int bg = blockIdx.x;                      // b*32 + g; 16384 contiguous floats
    const f32x4* p = (const f32x4*)(x + (size_t)bg * 16384);
    int t = threadIdx.x;
    float s = 0.f, sq = 0.f;
    for (int i = t; i < 4096; i += 256) {
        f32x4 v = p[i];
        #pragma unroll
        for (int j = 0; j < 4; ++j) { s += v[j]; sq += v[j] * v[j]; }
    }
    for (int off = 32; off > 0; off >>= 1) {
        s  += __shfl_down(s, off);
        sq += __shfl_down(sq, off);
    }
    __shared__ float red[8];
    int lane = t & 63, wv = t >> 6;
    if (lane == 0) { red[wv] = s; red[wv + 4] = sq; }
    __syncthreads();
    if (t == 0) {
        float ts = red[0] + red[1] + red[2] + red[3];
        float tq = red[4] + red[5] + red[6] + red[7];
        float mean = ts * (1.f / 16384.f);
        float var  = tq * (1.f / 16384.f) - mean * mean;
        stats[bg * 2]     = mean;
        stats[bg * 2 + 1] = rsqrtf(fmaxf(var, 0.f) + 1e-6f);
    }
}

// ---------------- fp32 -> bf16 conversion (two tensors per launch) ----------------
__global__ __launch_bounds__(256) void conv_kernel(
    const float* __restrict__ a, int na, unsigned short* __restrict__ da,
    const float* __restrict__ b, int nb, unsigned short* __restrict__ db)
{
    int i = blockIdx.x * 256 + threadIdx.x;
    if (i < na) da[i] = f2bf(a[i]);
    else if (i < na + nb) db[i - na] = f2bf(b[i - na]);
}

// ---------------- GN apply + transpose: x[b][c][n] fp32 -> xn[b][n][c] bf16 ----------------
__global__ __launch_bounds__(256) void xn_kernel(
    const float* __restrict__ x, const float* __restrict__ gw,
    const float* __restrict__ gb, const float* __restrict__ stats,
    unsigned short* __restrict__ xn)
{
    __shared__ unsigned short Tsh[64 * 66];   // [c_loc][n_loc], stride 66
    int n0 = blockIdx.x * 64, c0 = blockIdx.y * 64, b = blockIdx.z;
    int t = threadIdx.x;
    {
        int cl = t >> 2, n16 = (t & 3) * 16;
        int c = c0 + cl;
        const float* st = stats + ((size_t)b * 32 + (c >> 4)) * 2;
        float mean = st[0], rstd = st[1];
        float gam = gw[c], bet = gb[c];
        const float* xr = x + ((size_t)(b * CH + c)) * NTOK + n0 + n16;
        #pragma unroll
        for (int i = 0; i < 4; ++i) {
            f32x4 v = *(const f32x4*)(xr + i * 4);
            u16x2 p0 = { f2bf((v[0] - mean) * rstd * gam + bet),
                         f2bf((v[1] - mean) * rstd * gam + bet) };
            u16x2 p1 = { f2bf((v[2] - mean) * rstd * gam + bet),
                         f2bf((v[3] - mean) * rstd * gam + bet) };
            *(u16x2*)&Tsh[cl * 66 + n16 + i * 4]     = p0;
            *(u16x2*)&Tsh[cl * 66 + n16 + i * 4 + 2] = p1;
        }
    }
    __syncthreads();
    {
        int nl = t >> 2, c16 = (t & 3) * 16;
        u16x8 o0v, o1v;
        #pragma unroll
        for (int j = 0; j < 8; ++j) o0v[j] = Tsh[(c16 + j) * 66 + nl];
        #pragma unroll
        for (int j = 0; j < 8; ++j) o1v[j] = Tsh[(c16 + 8 + j) * 66 + nl];
        unsigned short* orow = xn + ((size_t)(b * NTOK + n0 + nl)) * CH + c0 + c16;
        *(u16x8*)orow       = o0v;
        *(u16x8*)(orow + 8) = o1v;
    }
}

// ---------------- QKV GEMM: qkv[o][token] = sum_c W[o][c] * xn[token][c] ----------------
// A = xn tokens (LDS tile), B = W rows (global bf16, L1-served). 64 tok x 128 o per block.
// o < 1024 -> qk[b][token][o] (token-major); o >= 1024 -> Vb[b][h][c][token] (packed u16x4).
__global__ __launch_bounds__(256) void qkv_gemm(
    const unsigned short* __restrict__ xn,   // [b][1024][512]
    const unsigned short* __restrict__ wq,   // [1536][512] bf16
    const unsigned short* __restrict__ bq,   // [1536] bf16
    unsigned short* __restrict__ qk,         // [b][1024][1024]
    unsigned short* __restrict__ vb)         // [b*8+h][64][1024]
{
    __shared__ __align__(16) unsigned short Ash[64 * 72];
    int n0 = blockIdx.x * 64, o0 = blockIdx.y * 128, b = blockIdx.z;
    int t = threadIdx.x, L = t & 63, wv = t >> 6, l15 = L & 15, qd = L >> 4;
    int nl = t >> 2, c16 = (t & 3) * 16;
    const unsigned short* xrow = xn + ((size_t)(b * NTOK + n0 + nl)) * CH + c16;

    f32x4 acc[8];
    #pragma unroll
    for (int i = 0; i < 8; ++i) acc[i] = (f32x4){0.f, 0.f, 0.f, 0.f};

    for (int kk = 0; kk < CH; kk += 64) {
        __syncthreads();
        *(u16x8*)&Ash[nl * 72 + c16]     = *(const u16x8*)(xrow + kk);
        *(u16x8*)&Ash[nl * 72 + c16 + 8] = *(const u16x8*)(xrow + kk + 8);
        __syncthreads();
        #pragma unroll
        for (int cc = 0; cc < 2; ++cc) {
            bf16x8 a = *(const bf16x8*)&Ash[(wv * 16 + l15) * 72 + cc * 32 + qd * 8];
            #pragma unroll
            for (int ns = 0; ns < 8; ++ns) {
                bf16x8 w8 = *(const bf16x8*)(wq + (size_t)(o0 + ns * 16 + l15) * CH + kk + cc * 32 + qd * 8);
                acc[ns] = __builtin_amdgcn_mfma_f32_16x16x32_bf16(a, w8, acc[ns], 0, 0, 0);
            }
        }
    }

    int tokb = n0 + wv * 16 + qd * 4;   // D row = token = tokb + r; col = o = o0+ns*16+l15
    if (o0 < 1024) {
        #pragma unroll
        for (int ns = 0; ns < 8; ++ns) {
            int o = o0 + ns * 16 + l15;
            float bias = bf2f(bq[o]);
            #pragma unroll
            for (int r = 0; r < 4; ++r)
                qk[((size_t)b * NTOK + tokb + r) * 1024 + o] = f2bf(acc[ns][r] + bias);
        }
    } else {
        #pragma unroll
        for (int ns = 0; ns < 8; ++ns) {
            int oo = o0 - 1024 + ns * 16 + l15;
            int h = oo >> 6, c = oo & 63;
            float bias = bf2f(bq[1024 + oo]);
            u16x4 pk;
            #pragma unroll
            for (int r = 0; r < 4; ++r) pk[r] = f2bf(acc[ns][r] + bias);
            *(u16x4*)&vb[((size_t)(b * 8 + h) * 64 + c) * NTOK + tokb] = pk;
        }
    }
}

// ---------------- MFMA flash attention (token-major qk, pre-transposed Vb) ----------------
__global__ __launch_bounds__(256) void attn_kernel(
    unsigned short* __restrict__ qk, const unsigned short* __restrict__ vb)
{
    __shared__ __align__(16) unsigned short Qsh[128 * 72];  // [n_loc][c]
    __shared__ __align__(16) unsigned short Ksh[64 * 72];   // [m_loc][c]
    __shared__ __align__(16) unsigned short Vsh[64 * 72];   // [c][m_loc]
    __shared__ __align__(16) unsigned short Psh[4][2560];   // per-wave P [n32][m64] s72

    int q0 = blockIdx.x * 128, h = blockIdx.y, b = blockIdx.z;
    int t = threadIdx.x, L = t & 63, wv = t >> 6, l15 = L & 15, qd = L >> 4;

    // stage Q (pre-scaled by 0.125)
    {
        int nl = t >> 1, c32 = (t & 1) * 32;
        const unsigned short* qrow = qk + ((size_t)b * NTOK + q0 + nl) * 1024 + h * 64 + c32;
        #pragma unroll
        for (int i = 0; i < 4; ++i) {
            u16x8 u = *(const u16x8*)(qrow + i * 8);
            u16x8 s;
            #pragma unroll
            for (int j = 0; j < 8; ++j) s[j] = f2bf(bf2f(u[j]) * 0.125f);
            *(u16x8*)&Qsh[nl * 72 + c32 + i * 8] = s;
        }
    }

    f32x4 Oacc[2][4];
    #pragma unroll
    for (int i = 0; i < 2; ++i)
        #pragma unroll
        for (int j = 0; j < 4; ++j) Oacc[i][j] = (f32x4){0.f, 0.f, 0.f, 0.f};
    float mrun[2] = {-1e30f, -1e30f}, lrun[2] = {0.f, 0.f};

    int ml = t >> 2, q16 = (t & 3) * 16;
    const unsigned short* vbase = vb + (size_t)(b * 8 + h) * 64 * NTOK;

    for (int m0 = 0; m0 < NTOK; m0 += 64) {
        __syncthreads();
        {
            const unsigned short* krow = qk + ((size_t)b * NTOK + m0 + ml) * 1024 + 512 + h * 64 + q16;
            *(u16x8*)&Ksh[ml * 72 + q16]     = *(const u16x8*)krow;
            *(u16x8*)&Ksh[ml * 72 + q16 + 8] = *(const u16x8*)(krow + 8);
            const unsigned short* vrow = vbase + (size_t)ml * NTOK + m0 + q16;   // ml = c here
            *(u16x8*)&Vsh[ml * 72 + q16]     = *(const u16x8*)vrow;
            *(u16x8*)&Vsh[ml * 72 + q16 + 8] = *(const u16x8*)(vrow + 8);
        }
        __syncthreads();

        // S^T[m][n] = K^T · Q
        f32x4 st[4][2];
        #pragma unroll
        for (int mt = 0; mt < 4; ++mt)
            #pragma unroll
            for (int nt = 0; nt < 2; ++nt) st[mt][nt] = (f32x4){0.f, 0.f, 0.f, 0.f};
        #pragma unroll
        for (int cc = 0; cc < 2; ++cc) {
            bf16x8 bq2[2];
            #pragma unroll
            for (int nt = 0; nt < 2; ++nt)
                bq2[nt] = *(const bf16x8*)&Qsh[(wv * 32 + nt * 16 + l15) * 72 + cc * 32 + qd * 8];
            #pragma unroll
            for (int mt = 0; mt < 4; ++mt) {
                bf16x8 a = *(const bf16x8*)&Ksh[(mt * 16 + l15) * 72 + cc * 32 + qd * 8];
                #pragma unroll
                for (int nt = 0; nt < 2; ++nt)
                    st[mt][nt] = __builtin_amdgcn_mfma_f32_16x16x32_bf16(a, bq2[nt], st[mt][nt], 0, 0, 0);
            }
        }

        // online softmax per query col n = nt*16 + l15 (replicated across quads)
        #pragma unroll
        for (int nt = 0; nt < 2; ++nt) {
            float tmax = -1e30f;
            #pragma unroll
            for (int mt = 0; mt < 4; ++mt)
                #pragma unroll
                for (int r = 0; r < 4; ++r) tmax = fmaxf(tmax, st[mt][nt][r]);
            tmax = fmaxf(tmax, __shfl_xor(tmax, 16));
            tmax = fmaxf(tmax, __shfl_xor(tmax, 32));
            float newm = fmaxf(mrun[nt], tmax);
            float alpha = __expf(mrun[nt] - newm);
            mrun[nt] = newm;
            float psum = 0.f;
            #pragma unroll
            for (int mt = 0; mt < 4; ++mt) {
                u16x4 pk;
                #pragma unroll
                for (int r = 0; r < 4; ++r) {
                    float p = __expf(st[mt][nt][r] - newm);
                    psum += p;
                    pk[r] = f2bf(p);
                }
                *(u16x4*)&Psh[wv][(nt * 16 + l15) * 72 + mt * 16 + 4 * qd] = pk;
            }
            psum += __shfl_xor(psum, 16);
            psum += __shfl_xor(psum, 32);
            lrun[nt] = lrun[nt] * alpha + psum;
            #pragma unroll
            for (int r = 0; r < 4; ++r) {
                float ar = __shfl(alpha, 4 * qd + r);
                #pragma unroll
                for (int ct = 0; ct < 4; ++ct) Oacc[nt][ct][r] *= ar;
            }
        }

        // O[n][c] += P · V^T
        #pragma unroll
        for (int mk = 0; mk < 2; ++mk) {
            bf16x8 ap[2];
            #pragma unroll
            for (int nt = 0; nt < 2; ++nt)
                ap[nt] = *(const bf16x8*)&Psh[wv][(nt * 16 + l15) * 72 + mk * 32 + qd * 8];
            #pragma unroll
            for (int ct = 0; ct < 4; ++ct) {
                bf16x8 bv = *(const bf16x8*)&Vsh[(ct * 16 + l15) * 72 + mk * 32 + qd * 8];
                #pragma unroll
                for (int nt = 0; nt < 2; ++nt)
                    Oacc[nt][ct] = __builtin_amdgcn_mfma_f32_16x16x32_bf16(ap[nt], bv, Oacc[nt][ct], 0, 0, 0);
            }
        }
    }

    // epilogue: direct coalesced stores into qk Q-region (in-place, own rows/cols only)
    #pragma unroll
    for (int nt = 0; nt < 2; ++nt) {
        float inv = 1.f / lrun[nt];
        #pragma unroll
        for (int r = 0; r < 4; ++r) {
            float ir = __shfl(inv, 4 * qd + r);
            int n = q0 + wv * 32 + nt * 16 + qd * 4 + r;
            unsigned short* orow = qk + ((size_t)b * NTOK + n) * 1024 + h * 64;
            #pragma unroll
            for (int ct = 0; ct < 4; ++ct)
                orow[ct * 16 + l15] = f2bf(Oacc[nt][ct][r] * ir);
        }
    }
}

// ---------------- proj GEMM + bias + residual, fp32 out ----------------
__global__ __launch_bounds__(256) void proj_gemm(
    const unsigned short* __restrict__ ao,   // qk base: cols [0,512) = attn out, row stride 1024
    const unsigned short* __restrict__ wp,   // [512][512] bf16
    const unsigned short* __restrict__ bp,   // [512] bf16
    const float* __restrict__ x,             // residual [b][512][1024]
    float* __restrict__ out)                 // [b][512][1024]
{
    __shared__ __align__(16) unsigned short Ash[64 * 72];
    int n0 = blockIdx.x * 64, o0 = blockIdx.y * 128, b = blockIdx.z;
    int t = threadIdx.x, L = t & 63, wv = t >> 6, l15 = L & 15, qd = L >> 4;
    int nl = t >> 2, c16 = (t & 3) * 16;
    const unsigned short* arow = ao + ((size_t)(b * NTOK + n0 + nl)) * 1024 + c16;

    f32x4 acc[8];
    #pragma unroll
    for (int i = 0; i < 8; ++i) acc[i] = (f32x4){0.f, 0.f, 0.f, 0.f};

    for (int kk = 0; kk < CH; kk += 64) {
        __syncthreads();
        *(u16x8*)&Ash[nl * 72 + c16]     = *(const u16x8*)(arow + kk);
        *(u16x8*)&Ash[nl * 72 + c16 + 8] = *(const u16x8*)(arow + kk + 8);
        __syncthreads();
        #pragma unroll
        for (int cc = 0; cc < 2; ++cc) {
            bf16x8 a = *(const bf16x8*)&Ash[(wv * 16 + l15) * 72 + cc * 32 + qd * 8];
            #pragma unroll
            for (int ns = 0; ns < 8; ++ns) {
                bf16x8 w8 = *(const bf16x8*)(wp + (size_t)(o0 + ns * 16 + l15) * CH + kk + cc * 32 + qd * 8);
                acc[ns] = __builtin_amdgcn_mfma_f32_16x16x32_bf16(a, w8, acc[ns], 0, 0, 0);
            }
        }
    }

    int tokb = n0 + wv * 16 + qd * 4;
    #pragma unroll
    for (int ns = 0; ns < 8; ++ns) {
        int o = o0 + ns * 16 + l15;
        float bias = bf2f(bp[o]);
        size_t base = ((size_t)(b * CH + o)) * NTOK + tokb;
        f32x4 res = *(const f32x4*)(x + base);
        f32x4 vv;
        #pragma unroll
        for (int r = 0; r < 4; ++r) vv[r] = acc[ns][r] + bias + res[r];
        *(f32x4*)(out + base) = vv;
    }
}

extern "C" void kernel_launch(void* const* d_in, const int* in_sizes, int n_in,
                              void* d_out, int out_size, void* d_ws, size_t ws_size,
                              hipStream_t stream) {
    const float* x      = (const float*)d_in[0];
    const float* norm_w = (const float*)d_in[1];
    const float* norm_b = (const float*)d_in[2];
    const float* qkv_w  = (const float*)d_in[3];
    const float* qkv_b  = (const float*)d_in[4];
    const float* proj_w = (const float*)d_in[5];
    const float* proj_b = (const float*)d_in[6];
    float* out = (float*)d_out;

    // ws: qk 16 MB | vb 8 MB  (exactly 24 MB, proven available)
    // wp/bp converted into the (dead) vb region AFTER attention.
    const size_t QK_B = (size_t)NB * NTOK * 1024 * 2;        // 16,777,216
    const size_t VB_B = (size_t)NB * 8 * 64 * NTOK * 2;      //  8,388,608
    if (ws_size < QK_B + VB_B) return;
    unsigned short* qk = (unsigned short*)d_ws;
    unsigned short* vb = (unsigned short*)((char*)d_ws + QK_B);
    unsigned short* wp = vb;                                  // alias: valid only after attn
    unsigned short* bp = vb + 512 * 512;

    // d_out scratch (dead before proj writes): xn 8 MB | wq 1.5 MB | bq | stats
    unsigned short* xn = (unsigned short*)d_out;                         // 8,388,608 B
    unsigned short* wq = (unsigned short*)((char*)d_out + 8388608);      // 1,572,864 B
    unsigned short* bq = (unsigned short*)((char*)d_out + 9961472);      // 3,072 B
    float* stats = (float*)((char*)d_out + 9964544);                     // 2,048 B

    stats_kernel<<<dim3(256), dim3(256), 0, stream>>>(x, stats);
    conv_kernel<<<dim3(3078), dim3(256), 0, stream>>>(qkv_w, 786432, wq, qkv_b, 1536, bq);
    xn_kernel<<<dim3(16, 8, NB), dim3(256), 0, stream>>>(x, norm_w, norm_b, stats, xn);
    qkv_gemm<<<dim3(16, 12, NB), dim3(256), 0, stream>>>(xn, wq, bq, qk, vb);
    attn_kernel<<<dim3(8, 8, NB), dim3(256), 0, stream>>>(qk, vb);
    conv_kernel<<<dim3(1026), dim3(256), 0, stream>>>(proj_w, 262144, wp, proj_b, 512, bp);
    proj_gemm<<<dim3(16, 4, NB), dim3(256), 0, stream>>>(qk, wp, bp, x, out);
}

// Round 6
// 179.424 us; speedup vs baseline: 1.6225x; 1.6225x over previous
//
#include <hip/hip_runtime.h>
#include <math.h>

#define NB 8
#define CH 512
#define NTOK 1024

typedef short          bf16x8 __attribute__((ext_vector_type(8)));
typedef unsigned short u16x8  __attribute__((ext_vector_type(8)));
typedef unsigned short u16x4  __attribute__((ext_vector_type(4)));
typedef unsigned short u16x2  __attribute__((ext_vector_type(2)));
typedef float          f32x4  __attribute__((ext_vector_type(4)));

__device__ __forceinline__ float bf2f(unsigned short u) {
    unsigned int x = ((unsigned int)u) << 16;
    return __builtin_bit_cast(float, x);
}
__device__ __forceinline__ unsigned short f2bf(float f) {
    unsigned int x = __builtin_bit_cast(unsigned int, f);
    x += 0x7fff + ((x >> 16) & 1);   // RNE
    return (unsigned short)(x >> 16);
}

// async global->LDS, 16B per lane; LDS dest = base + lane*16 (wave-uniform base)
__device__ __forceinline__ void async16(const void* g, void* l) {
    __builtin_amdgcn_global_load_lds(
        (const __attribute__((address_space(1))) unsigned int*)g,
        (__attribute__((address_space(3))) unsigned int*)l, 16, 0, 0);
}

// ---------------- GroupNorm stats: one block per (b, group) ----------------
__global__ __launch_bounds__(256) void stats_kernel(
    const float* __restrict__ x, float* __restrict__ stats)
{
    int bg = blockIdx.x;
    const f32x4* p = (const f32x4*)(x + (size_t)bg * 16384);
    int t = threadIdx.x;
    float s = 0.f, sq = 0.f;
    for (int i = t; i < 4096; i += 256) {
        f32x4 v = p[i];
        #pragma unroll
        for (int j = 0; j < 4; ++j) { s += v[j]; sq += v[j] * v[j]; }
    }
    for (int off = 32; off > 0; off >>= 1) {
        s  += __shfl_down(s, off);
        sq += __shfl_down(sq, off);
    }
    __shared__ float red[8];
    int lane = t & 63, wv = t >> 6;
    if (lane == 0) { red[wv] = s; red[wv + 4] = sq; }
    __syncthreads();
    if (t == 0) {
        float ts = red[0] + red[1] + red[2] + red[3];
        float tq = red[4] + red[5] + red[6] + red[7];
        float mean = ts * (1.f / 16384.f);
        float var  = tq * (1.f / 16384.f) - mean * mean;
        stats[bg * 2]     = mean;
        stats[bg * 2 + 1] = rsqrtf(fmaxf(var, 0.f) + 1e-6f);
    }
}

// ---------------- fp32 -> bf16 conversion (two tensors per launch) ----------------
__global__ __launch_bounds__(256) void conv_kernel(
    const float* __restrict__ a, int na, unsigned short* __restrict__ da,
    const float* __restrict__ b, int nb, unsigned short* __restrict__ db)
{
    int i = blockIdx.x * 256 + threadIdx.x;
    if (i < na) da[i] = f2bf(a[i]);
    else if (i < na + nb) db[i - na] = f2bf(b[i - na]);
}

// ---------------- GN apply + transpose: x[b][c][n] fp32 -> xn[b][n][c] bf16 ----------------
__global__ __launch_bounds__(256) void xn_kernel(
    const float* __restrict__ x, const float* __restrict__ gw,
    const float* __restrict__ gb, const float* __restrict__ stats,
    unsigned short* __restrict__ xn)
{
    __shared__ unsigned short Tsh[64 * 66];
    int n0 = blockIdx.x * 64, c0 = blockIdx.y * 64, b = blockIdx.z;
    int t = threadIdx.x;
    {
        int cl = t >> 2, n16 = (t & 3) * 16;
        int c = c0 + cl;
        const float* st = stats + ((size_t)b * 32 + (c >> 4)) * 2;
        float mean = st[0], rstd = st[1];
        float gam = gw[c], bet = gb[c];
        const float* xr = x + ((size_t)(b * CH + c)) * NTOK + n0 + n16;
        #pragma unroll
        for (int i = 0; i < 4; ++i) {
            f32x4 v = *(const f32x4*)(xr + i * 4);
            u16x2 p0 = { f2bf((v[0] - mean) * rstd * gam + bet),
                         f2bf((v[1] - mean) * rstd * gam + bet) };
            u16x2 p1 = { f2bf((v[2] - mean) * rstd * gam + bet),
                         f2bf((v[3] - mean) * rstd * gam + bet) };
            *(u16x2*)&Tsh[cl * 66 + n16 + i * 4]     = p0;
            *(u16x2*)&Tsh[cl * 66 + n16 + i * 4 + 2] = p1;
        }
    }
    __syncthreads();
    {
        int nl = t >> 2, c16 = (t & 3) * 16;
        u16x8 o0v, o1v;
        #pragma unroll
        for (int j = 0; j < 8; ++j) o0v[j] = Tsh[(c16 + j) * 66 + nl];
        #pragma unroll
        for (int j = 0; j < 8; ++j) o1v[j] = Tsh[(c16 + 8 + j) * 66 + nl];
        unsigned short* orow = xn + ((size_t)(b * NTOK + n0 + nl)) * CH + c0 + c16;
        *(u16x8*)orow       = o0v;
        *(u16x8*)(orow + 8) = o1v;
    }
}

// ================= m97-style GEMM core (128 tok x 128 out, BK=64) =================
// LDS[r][cs] = X[r][kk + (cs ^ (r&7)*8)]; frag offset sw = (cc*32+qd*8) ^ ((l15&7)*8).
#define GEMM_CORE(XPTR, XPITCH, WPTR)                                            \
    __shared__ __align__(16) unsigned short Ash[128 * 64];                       \
    __shared__ __align__(16) unsigned short Wsh[128 * 64];                       \
    int n0 = blockIdx.x * 128, o0 = blockIdx.y * 128, b = blockIdx.z;            \
    int t = threadIdx.x, L = t & 63, wv = t >> 6, l15 = L & 15, qd = L >> 4;     \
    int to0 = (wv & 1) * 64, wo0 = (wv >> 1) * 64;                               \
    int srow = L >> 3;                                                           \
    int scol = ((L & 7) ^ srow) * 8;                                             \
    const unsigned short* abase = (XPTR) + ((size_t)(b * NTOK + n0 + srow)) * (XPITCH) + scol; \
    const unsigned short* wbase = (WPTR) + ((size_t)(o0 + srow)) * CH + scol;    \
    f32x4 acc[4][4];                                                             \
    _Pragma("unroll")                                                            \
    for (int i = 0; i < 4; ++i)                                                  \
        _Pragma("unroll")                                                        \
        for (int j = 0; j < 4; ++j) acc[i][j] = (f32x4){0.f, 0.f, 0.f, 0.f};     \
    for (int kk = 0; kk < CH; kk += 64) {                                        \
        __syncthreads();                                                         \
        _Pragma("unroll")                                                        \
        for (int j = 0; j < 4; ++j) {                                            \
            int is = wv * 4 + j;                                                 \
            async16(abase + (size_t)is * 8 * (XPITCH) + kk, &Ash[is * 512]);     \
            async16(wbase + (size_t)is * 8 * CH + kk, &Wsh[is * 512]);           \
        }                                                                        \
        __syncthreads();                                                         \
        _Pragma("unroll")                                                        \
        for (int cc = 0; cc < 2; ++cc) {                                         \
            int sw = (cc * 32 + qd * 8) ^ ((l15 & 7) * 8);                       \
            bf16x8 af[4], bfr[4];                                                \
            _Pragma("unroll")                                                    \
            for (int mi = 0; mi < 4; ++mi)                                       \
                af[mi] = *(const bf16x8*)&Ash[(to0 + mi * 16 + l15) * 64 + sw];  \
            _Pragma("unroll")                                                    \
            for (int ni = 0; ni < 4; ++ni)                                       \
                bfr[ni] = *(const bf16x8*)&Wsh[(wo0 + ni * 16 + l15) * 64 + sw]; \
            _Pragma("unroll")                                                    \
            for (int mi = 0; mi < 4; ++mi)                                       \
                _Pragma("unroll")                                                \
                for (int ni = 0; ni < 4; ++ni)                                   \
                    acc[mi][ni] = __builtin_amdgcn_mfma_f32_16x16x32_bf16(       \
                        af[mi], bfr[ni], acc[mi][ni], 0, 0, 0);                  \
        }                                                                        \
    }

// ---------------- QKV GEMM ----------------
__global__ __launch_bounds__(256) void qkv_gemm(
    const unsigned short* __restrict__ xn,   // [b][1024][512]
    const unsigned short* __restrict__ wq,   // [1536][512]
    const unsigned short* __restrict__ bq,   // [1536]
    unsigned short* __restrict__ qk,         // [b][1024][1024]
    unsigned short* __restrict__ vb)         // [b*8+h][64][1024]
{
    GEMM_CORE(xn, CH, wq)

    if (o0 < 1024) {
        #pragma unroll
        for (int ni = 0; ni < 4; ++ni) {
            int o = o0 + wo0 + ni * 16 + l15;
            float bias = bf2f(bq[o]);
            #pragma unroll
            for (int mi = 0; mi < 4; ++mi) {
                int tok = n0 + to0 + mi * 16 + qd * 4;
                #pragma unroll
                for (int r = 0; r < 4; ++r)
                    qk[((size_t)b * NTOK + tok + r) * 1024 + o] = f2bf(acc[mi][ni][r] + bias);
            }
        }
    } else {
        #pragma unroll
        for (int ni = 0; ni < 4; ++ni) {
            int oo = o0 - 1024 + wo0 + ni * 16 + l15;
            int h = oo >> 6, c = oo & 63;
            float bias = bf2f(bq[1024 + oo]);
            #pragma unroll
            for (int mi = 0; mi < 4; ++mi) {
                int tok = n0 + to0 + mi * 16 + qd * 4;
                u16x4 pk;
                #pragma unroll
                for (int r = 0; r < 4; ++r) pk[r] = f2bf(acc[mi][ni][r] + bias);
                *(u16x4*)&vb[((size_t)(b * 8 + h) * 64 + c) * NTOK + tok] = pk;
            }
        }
    }
}

// ---------------- proj GEMM + bias + residual, fp32 out ----------------
__global__ __launch_bounds__(256) void proj_gemm(
    const unsigned short* __restrict__ ao,   // qk: cols [0,512) attn out, pitch 1024
    const unsigned short* __restrict__ wp,   // [512][512]
    const unsigned short* __restrict__ bp,   // [512]
    const float* __restrict__ x,             // residual [b][512][1024]
    float* __restrict__ out)                 // [b][512][1024]
{
    GEMM_CORE(ao, 1024, wp)

    #pragma unroll
    for (int ni = 0; ni < 4; ++ni) {
        int o = o0 + wo0 + ni * 16 + l15;
        float bias = bf2f(bp[o]);
        #pragma unroll
        for (int mi = 0; mi < 4; ++mi) {
            int tok = n0 + to0 + mi * 16 + qd * 4;
            size_t base = ((size_t)(b * CH + o)) * NTOK + tok;
            f32x4 res = *(const f32x4*)(x + base);
            f32x4 vv;
            #pragma unroll
            for (int r = 0; r < 4; ++r) vv[r] = acc[mi][ni][r] + bias + res[r];
            *(f32x4*)(out + base) = vv;
        }
    }
}

// ---------------- MFMA flash attention (unchanged, known-good) ----------------
__global__ __launch_bounds__(256) void attn_kernel(
    unsigned short* __restrict__ qk, const unsigned short* __restrict__ vb)
{
    __shared__ __align__(16) unsigned short Qsh[128 * 72];
    __shared__ __align__(16) unsigned short Ksh[64 * 72];
    __shared__ __align__(16) unsigned short Vsh[64 * 72];
    __shared__ __align__(16) unsigned short Psh[4][2560];

    int q0 = blockIdx.x * 128, h = blockIdx.y, b = blockIdx.z;
    int t = threadIdx.x, L = t & 63, wv = t >> 6, l15 = L & 15, qd = L >> 4;

    {
        int nl = t >> 1, c32 = (t & 1) * 32;
        const unsigned short* qrow = qk + ((size_t)b * NTOK + q0 + nl) * 1024 + h * 64 + c32;
        #pragma unroll
        for (int i = 0; i < 4; ++i) {
            u16x8 u = *(const u16x8*)(qrow + i * 8);
            u16x8 s;
            #pragma unroll
            for (int j = 0; j < 8; ++j) s[j] = f2bf(bf2f(u[j]) * 0.125f);
            *(u16x8*)&Qsh[nl * 72 + c32 + i * 8] = s;
        }
    }

    f32x4 Oacc[2][4];
    #pragma unroll
    for (int i = 0; i < 2; ++i)
        #pragma unroll
        for (int j = 0; j < 4; ++j) Oacc[i][j] = (f32x4){0.f, 0.f, 0.f, 0.f};
    float mrun[2] = {-1e30f, -1e30f}, lrun[2] = {0.f, 0.f};

    int ml = t >> 2, q16 = (t & 3) * 16;
    const unsigned short* vbase = vb + (size_t)(b * 8 + h) * 64 * NTOK;

    for (int m0 = 0; m0 < NTOK; m0 += 64) {
        __syncthreads();
        {
            const unsigned short* krow = qk + ((size_t)b * NTOK + m0 + ml) * 1024 + 512 + h * 64 + q16;
            *(u16x8*)&Ksh[ml * 72 + q16]     = *(const u16x8*)krow;
            *(u16x8*)&Ksh[ml * 72 + q16 + 8] = *(const u16x8*)(krow + 8);
            const unsigned short* vrow = vbase + (size_t)ml * NTOK + m0 + q16;
            *(u16x8*)&Vsh[ml * 72 + q16]     = *(const u16x8*)vrow;
            *(u16x8*)&Vsh[ml * 72 + q16 + 8] = *(const u16x8*)(vrow + 8);
        }
        __syncthreads();

        f32x4 st[4][2];
        #pragma unroll
        for (int mt = 0; mt < 4; ++mt)
            #pragma unroll
            for (int nt = 0; nt < 2; ++nt) st[mt][nt] = (f32x4){0.f, 0.f, 0.f, 0.f};
        #pragma unroll
        for (int cc = 0; cc < 2; ++cc) {
            bf16x8 bq2[2];
            #pragma unroll
            for (int nt = 0; nt < 2; ++nt)
                bq2[nt] = *(const bf16x8*)&Qsh[(wv * 32 + nt * 16 + l15) * 72 + cc * 32 + qd * 8];
            #pragma unroll
            for (int mt = 0; mt < 4; ++mt) {
                bf16x8 a = *(const bf16x8*)&Ksh[(mt * 16 + l15) * 72 + cc * 32 + qd * 8];
                #pragma unroll
                for (int nt = 0; nt < 2; ++nt)
                    st[mt][nt] = __builtin_amdgcn_mfma_f32_16x16x32_bf16(a, bq2[nt], st[mt][nt], 0, 0, 0);
            }
        }

        #pragma unroll
        for (int nt = 0; nt < 2; ++nt) {
            float tmax = -1e30f;
            #pragma unroll
            for (int mt = 0; mt < 4; ++mt)
                #pragma unroll
                for (int r = 0; r < 4; ++r) tmax = fmaxf(tmax, st[mt][nt][r]);
            tmax = fmaxf(tmax, __shfl_xor(tmax, 16));
            tmax = fmaxf(tmax, __shfl_xor(tmax, 32));
            float newm = fmaxf(mrun[nt], tmax);
            float alpha = __expf(mrun[nt] - newm);
            mrun[nt] = newm;
            float psum = 0.f;
            #pragma unroll
            for (int mt = 0; mt < 4; ++mt) {
                u16x4 pk;
                #pragma unroll
                for (int r = 0; r < 4; ++r) {
                    float p = __expf(st[mt][nt][r] - newm);
                    psum += p;
                    pk[r] = f2bf(p);
                }
                *(u16x4*)&Psh[wv][(nt * 16 + l15) * 72 + mt * 16 + 4 * qd] = pk;
            }
            psum += __shfl_xor(psum, 16);
            psum += __shfl_xor(psum, 32);
            lrun[nt] = lrun[nt] * alpha + psum;
            #pragma unroll
            for (int r = 0; r < 4; ++r) {
                float ar = __shfl(alpha, 4 * qd + r);
                #pragma unroll
                for (int ct = 0; ct < 4; ++ct) Oacc[nt][ct][r] *= ar;
            }
        }

        #pragma unroll
        for (int mk = 0; mk < 2; ++mk) {
            bf16x8 ap[2];
            #pragma unroll
            for (int nt = 0; nt < 2; ++nt)
                ap[nt] = *(const bf16x8*)&Psh[wv][(nt * 16 + l15) * 72 + mk * 32 + qd * 8];
            #pragma unroll
            for (int ct = 0; ct < 4; ++ct) {
                bf16x8 bv = *(const bf16x8*)&Vsh[(ct * 16 + l15) * 72 + mk * 32 + qd * 8];
                #pragma unroll
                for (int nt = 0; nt < 2; ++nt)
                    Oacc[nt][ct] = __builtin_amdgcn_mfma_f32_16x16x32_bf16(ap[nt], bv, Oacc[nt][ct], 0, 0, 0);
            }
        }
    }

    #pragma unroll
    for (int nt = 0; nt < 2; ++nt) {
        float inv = 1.f / lrun[nt];
        #pragma unroll
        for (int r = 0; r < 4; ++r) {
            float ir = __shfl(inv, 4 * qd + r);
            int n = q0 + wv * 32 + nt * 16 + qd * 4 + r;
            unsigned short* orow = qk + ((size_t)b * NTOK + n) * 1024 + h * 64;
            #pragma unroll
            for (int ct = 0; ct < 4; ++ct)
                orow[ct * 16 + l15] = f2bf(Oacc[nt][ct][r] * ir);
        }
    }
}

extern "C" void kernel_launch(void* const* d_in, const int* in_sizes, int n_in,
                              void* d_out, int out_size, void* d_ws, size_t ws_size,
                              hipStream_t stream) {
    const float* x      = (const float*)d_in[0];
    const float* norm_w = (const float*)d_in[1];
    const float* norm_b = (const float*)d_in[2];
    const float* qkv_w  = (const float*)d_in[3];
    const float* qkv_b  = (const float*)d_in[4];
    const float* proj_w = (const float*)d_in[5];
    const float* proj_b = (const float*)d_in[6];
    float* out = (float*)d_out;

    const size_t QK_B = (size_t)NB * NTOK * 1024 * 2;        // 16 MB
    const size_t VB_B = (size_t)NB * 8 * 64 * NTOK * 2;      //  8 MB
    if (ws_size < QK_B + VB_B) return;
    unsigned short* qk = (unsigned short*)d_ws;
    unsigned short* vb = (unsigned short*)((char*)d_ws + QK_B);
    unsigned short* wp = vb;                                  // alias: valid after attn
    unsigned short* bp = vb + 512 * 512;

    unsigned short* xn = (unsigned short*)d_out;                         // 8 MB
    unsigned short* wq = (unsigned short*)((char*)d_out + 8388608);      // 1.5 MB
    unsigned short* bq = (unsigned short*)((char*)d_out + 9961472);
    float* stats = (float*)((char*)d_out + 9964544);

    stats_kernel<<<dim3(256), dim3(256), 0, stream>>>(x, stats);
    conv_kernel<<<dim3(3078), dim3(256), 0, stream>>>(qkv_w, 786432, wq, qkv_b, 1536, bq);
    xn_kernel<<<dim3(16, 8, NB), dim3(256), 0, stream>>>(x, norm_w, norm_b, stats, xn);
    qkv_gemm<<<dim3(8, 12, NB), dim3(256), 0, stream>>>(xn, wq, bq, qk, vb);
    attn_kernel<<<dim3(8, 8, NB), dim3(256), 0, stream>>>(qk, vb);
    conv_kernel<<<dim3(1026), dim3(256), 0, stream>>>(proj_w, 262144, wp, proj_b, 512, bp);
    proj_gemm<<<dim3(8, 4, NB), dim3(256), 0, stream>>>(qk, wp, bp, x, out);
}